// Round 9
// baseline (351.233 us; speedup 1.0000x reference)
//
#include <hip/hip_runtime.h>
#include <hip/hip_bf16.h>
#include <stdint.h>

typedef float f32x4 __attribute__((ext_vector_type(4)));
typedef float f32x16 __attribute__((ext_vector_type(16)));
typedef __bf16 bf16x8 __attribute__((ext_vector_type(8)));

#define EPS 1e-5f

// ---- helpers ----
static __device__ __forceinline__ unsigned short f2bf(float f) {
  unsigned int u = __float_as_uint(f);
  unsigned int r = (u + 0x7fffu + ((u >> 16) & 1u)) >> 16;
  return (unsigned short)r;
}

static __device__ __forceinline__ void gload_lds16(const unsigned short* g, unsigned short* s) {
  __builtin_amdgcn_global_load_lds((const __attribute__((address_space(1))) unsigned int*)g,
                                   (__attribute__((address_space(3))) unsigned int*)s,
                                   16, 0, 0);
}

// ---- fused head: W_uv -> bf16 convert  |  alpha = sigmoid(A Wa^T + b) + A->bf16 ----
__global__ __launch_bounds__(256) void k_head(const float* __restrict__ Wsrc,
                                              unsigned short* __restrict__ Wb,
                                              const float* __restrict__ A,
                                              const float* __restrict__ Wa,
                                              const float* __restrict__ ba,
                                              float* __restrict__ alpha,
                                              unsigned short* __restrict__ Ab) {
  __shared__ __align__(16) float arow[1024];
  if (blockIdx.x < 4096) {
    // convert W_uv (cached writes: Wb re-read by gemm)
    const int n4 = (16896 * 1024) / 4;
    int idx = blockIdx.x * 256 + threadIdx.x;
    for (int i = idx; i < n4; i += 4096 * 256) {
      f32x4 v = ((const f32x4*)Wsrc)[i];
      ushort4 o;
      o.x = f2bf(v.x); o.y = f2bf(v.y); o.z = f2bf(v.z); o.w = f2bf(v.w);
      ((ushort4*)Wb)[i] = o;
    }
    return;
  }
  const int bt = blockIdx.x - 4096, tid = threadIdx.x;
  f32x4 v = ((const f32x4*)(A + (size_t)bt * 1024))[tid];
  ((f32x4*)arow)[tid] = v;
  ushort4 o;
  o.x = f2bf(v.x); o.y = f2bf(v.y); o.z = f2bf(v.z); o.w = f2bf(v.w);
  ((ushort4*)(Ab + (size_t)bt * 1024))[tid] = o;
  __syncthreads();
  const int c = tid >> 3, h = tid & 7;
  const float* wr = Wa + (size_t)c * 1024 + h * 128;
  const float* ar = arow + h * 128;
  float s = 0.f;
#pragma unroll 8
  for (int j = 0; j < 128; j += 4) {
    f32x4 wv = *(const f32x4*)(wr + j);
    s += wv.x * ar[j] + wv.y * ar[j + 1] + wv.z * ar[j + 2] + wv.w * ar[j + 3];
  }
  s += __shfl_down(s, 4);
  s += __shfl_down(s, 2);
  s += __shfl_down(s, 1);
  if (h == 0) {
    float z = s + ba[c];
    alpha[(size_t)bt * 32 + c] = 1.f / (1.f + __expf(-z));
  }
}

// ---- main GEMM: C[4096,16896] = A[4096,1024] @ W^T, bf16, 256^2 8-phase ----
// BM=BN=256 BK=64, 8 waves (2Mx4N), per-wave 128x64 out, 128 KiB LDS dbuf.
// Conflict-free LDS swizzle (R6: conflicts->0). LGKM8 kept (R7). Plain C
// stores (R8: nontemporal doubled WRITE_SIZE -- sub-line stores need L2
// write-combining). This rev isolates tm-fast grid (R6 FETCH 324->178 MB,
// previously confounded with LGKM8 removal).

#define SWZ(b) ((b) ^ ((((b) >> 7) & 7) << 4))

#define STG(mat, off, ldsoff) \
  gload_lds16((const unsigned short*)((const char*)(mat) + (unsigned)(off)), \
              (unsigned short*)(smem + (ldsoff) + widK))

#define READ_A(p0, p1, qm) do {                                                 \
  _Pragma("unroll") for (int _mi = 0; _mi < 4; ++_mi) {                         \
    af[_mi][0] = *(const bf16x8*)((p0) + (qm) * 8192 + _mi * 2048);             \
    af[_mi][1] = *(const bf16x8*)((p1) + (qm) * 8192 + _mi * 2048);             \
  } } while (0)

#define READ_B(p0, p1, qn) do {                                                 \
  _Pragma("unroll") for (int _ni = 0; _ni < 2; ++_ni) {                         \
    bfr[qn][_ni][0] = *(const bf16x8*)((p0) + (qn) * 4096 + _ni * 2048);        \
    bfr[qn][_ni][1] = *(const bf16x8*)((p1) + (qn) * 4096 + _ni * 2048);        \
  } } while (0)

#define MMA(qm, qn) do {                                                        \
  __builtin_amdgcn_s_setprio(1);                                                \
  _Pragma("unroll") for (int _mi = 0; _mi < 4; ++_mi)                           \
  _Pragma("unroll") for (int _ni = 0; _ni < 2; ++_ni)                           \
  _Pragma("unroll") for (int _ks = 0; _ks < 2; ++_ks)                           \
    acc[(qm) * 4 + _mi][(qn) * 2 + _ni] = __builtin_amdgcn_mfma_f32_16x16x32_bf16( \
        af[_mi][_ks], bfr[qn][_ni][_ks], acc[(qm) * 4 + _mi][(qn) * 2 + _ni], 0, 0, 0); \
  __builtin_amdgcn_s_setprio(0);                                                \
  } while (0)

#define PH_SYNC do {                                                            \
  __builtin_amdgcn_s_barrier();                                                 \
  asm volatile("s_waitcnt lgkmcnt(0)" ::: "memory");                            \
  __builtin_amdgcn_sched_barrier(0);                                            \
  } while (0)

#define ENDBAR __builtin_amdgcn_s_barrier()
#define VMW4 asm volatile("s_waitcnt vmcnt(4)" ::: "memory")
#define VMW0 asm volatile("s_waitcnt vmcnt(0)" ::: "memory")
#define LGKM8 asm volatile("s_waitcnt lgkmcnt(8)" ::: "memory")

__global__ __launch_bounds__(512, 2) void k_gemm8(const unsigned short* __restrict__ A,
                                                  const unsigned short* __restrict__ W,
                                                  unsigned short* __restrict__ C) {
  extern __shared__ char smem[];  // 131072 B: buf{0,1} x {A0 A1 | B0 B1} 16K regions
  const int bid = blockIdx.x;
  const int tm = bid & 15, tn = bid >> 4;  // tm-fast: A L3-hot, W streamed once
  const int m0 = tm << 8, n0 = tn << 8;
  const int tid = threadIdx.x;
  const int lane = tid & 63;
  const int wid = tid >> 6;
  const int wm = wid >> 2, wn = wid & 3;
  const int fr = lane & 15, fq = lane >> 4;
  const int widK = wid * 1024;

  // staging global byte-offsets (pre-swizzled source, linear LDS dest)
  const int sb0 = SWZ(tid * 16);
  const int sb1 = SWZ(8192 + tid * 16);
  const int oB0_0 = (n0 + (sb0 >> 7)) * 2048 + (sb0 & 127);
  const int oB0_1 = (n0 + (sb1 >> 7)) * 2048 + (sb1 & 127);
  const int oB1_0 = oB0_0 + 128 * 2048;
  const int oB1_1 = oB0_1 + 128 * 2048;
  const int oA0_0 = (m0 + (sb0 >> 7)) * 2048 + (sb0 & 127);
  const int oA0_1 = (m0 + (sb1 >> 7)) * 2048 + (sb1 & 127);
  const int oA1_0 = oA0_0 + 128 * 2048;
  const int oA1_1 = oA0_1 + 128 * 2048;

  // ds_read bases: swizzled slot = ((ks<<2)|fq) ^ (fr&7); row term fr*128.
  const int lane0 = fr * 128 + ((fq ^ (fr & 7)) << 4);        // ks=0
  const int lane1 = fr * 128 + (((4 | fq) ^ (fr & 7)) << 4);  // ks=1
  char* const aK0b0 = smem + wm * 16384 + lane0;
  char* const aK1b0 = smem + wm * 16384 + lane1;
  char* const aK0b1 = aK0b0 + 65536;
  char* const aK1b1 = aK1b0 + 65536;
  char* const bb = smem + 32768 + (wn >> 1) * 16384 + (wn & 1) * 8192;
  char* const bK0b0 = bb + lane0;
  char* const bK1b0 = bb + lane1;
  char* const bK0b1 = bK0b0 + 65536;
  char* const bK1b1 = bK1b0 + 65536;

  f32x4 acc[8][4];
#pragma unroll
  for (int i = 0; i < 8; ++i)
#pragma unroll
    for (int j = 0; j < 4; ++j) acc[i][j] = (f32x4){0.f, 0.f, 0.f, 0.f};

  bf16x8 af[4][2];
  bf16x8 bfr[2][2][2];

  // prologue: K0 full (buf0) + K1 B-halves (buf1); leave K1 B in flight
  STG(W, oB0_0, 32768); STG(W, oB0_1, 40960);
  STG(W, oB1_0, 49152); STG(W, oB1_1, 57344);
  STG(A, oA0_0, 0);     STG(A, oA0_1, 8192);
  STG(A, oA1_0, 16384); STG(A, oA1_1, 24576);
  STG(W, oB0_0 + 128, 98304);  STG(W, oB0_1 + 128, 106496);
  STG(W, oB1_0 + 128, 114688); STG(W, oB1_1 + 128, 122880);
  VMW4;
  __builtin_amdgcn_s_barrier();

  for (int i = 0; i < 8; ++i) {
    const int kb1 = 256 * i + 128, kb2 = kb1 + 128, kb3 = kb2 + 128;
    // ph0: T0 q(0,0) | stage T1 A0 (buf1)
    READ_A(aK0b0, aK1b0, 0); READ_B(bK0b0, bK1b0, 0);
    STG(A, oA0_0 + kb1, 65536); STG(A, oA0_1 + kb1, 73728);
    LGKM8;
    PH_SYNC; MMA(0, 0); ENDBAR;
    // ph1: T0 q(0,1) | stage T1 A1
    READ_B(bK0b0, bK1b0, 1);
    STG(A, oA1_0 + kb1, 81920); STG(A, oA1_1 + kb1, 90112);
    PH_SYNC; MMA(0, 1); ENDBAR;
    // ph2: T0 q(1,0) | stage T2 B0 (buf0)
    READ_A(aK0b0, aK1b0, 1);
    if (i < 7) { STG(W, oB0_0 + kb2, 32768); STG(W, oB0_1 + kb2, 40960); }
    PH_SYNC; MMA(1, 0); ENDBAR;
    // ph3: T0 q(1,1) | stage T2 B1 ; ensure T1 fully landed
    if (i < 7) { STG(W, oB1_0 + kb2, 49152); STG(W, oB1_1 + kb2, 57344); VMW4; }
    else { VMW0; }
    PH_SYNC; MMA(1, 1); ENDBAR;
    // ph4: T1 q(0,0) | stage T2 A0 (buf0)
    READ_A(aK0b1, aK1b1, 0); READ_B(bK0b1, bK1b1, 0);
    if (i < 7) { STG(A, oA0_0 + kb2, 0); STG(A, oA0_1 + kb2, 8192); }
    LGKM8;
    PH_SYNC; MMA(0, 0); ENDBAR;
    // ph5: T1 q(0,1) | stage T2 A1
    READ_B(bK0b1, bK1b1, 1);
    if (i < 7) { STG(A, oA1_0 + kb2, 16384); STG(A, oA1_1 + kb2, 24576); }
    PH_SYNC; MMA(0, 1); ENDBAR;
    // ph6: T1 q(1,0) | stage T3 B0 (buf1)
    READ_A(aK0b1, aK1b1, 1);
    if (i < 7) { STG(W, oB0_0 + kb3, 98304); STG(W, oB0_1 + kb3, 106496); }
    PH_SYNC; MMA(1, 0); ENDBAR;
    // ph7: T1 q(1,1) | stage T3 B1 ; ensure T2 fully landed
    if (i < 7) { STG(W, oB1_0 + kb3, 114688); STG(W, oB1_1 + kb3, 122880); }
    VMW4;
    PH_SYNC; MMA(1, 1); ENDBAR;
  }

  // epilogue: C write (bf16), plain cached stores (L2 write-combining)
#pragma unroll
  for (int am = 0; am < 8; ++am)
#pragma unroll
    for (int an = 0; an < 4; ++an)
#pragma unroll
      for (int r = 0; r < 4; ++r) {
        int row = m0 + (wm << 7) + (am << 4) + (fq << 2) + r;
        int col = n0 + (wn << 6) + (an << 4) + fr;
        C[(size_t)row * 16896 + col] = f2bf(acc[am][an][r]);
      }
}

// ---- epilogue: per n (one wave): U from triu params, S = U U^T via one
//      32x32x16 MFMA pair; reductions lane-local + 1 shfl (32x32 C/D layout).
__global__ __launch_bounds__(256) void k_epi(const unsigned short* __restrict__ P,
                                             const float* __restrict__ X,
                                             const float* __restrict__ alpha,
                                             float* __restrict__ out) {
  __shared__ __align__(16) unsigned short U[4][1280];  // [wave][32 rows x 40 stride]
  __shared__ __align__(16) float Xl[4][32];
  __shared__ unsigned short tab[528];
  const int tid = threadIdx.x;
  for (int e = tid; e < 528; e += 256) {
    float fi = (65.0f - sqrtf((float)(4225 - 8 * e))) * 0.5f;
    int i = (int)fi;
    int oi = (i * (65 - i)) >> 1;
    if (e < oi) { --i; oi = (i * (65 - i)) >> 1; }
    else { int oi1 = ((i + 1) * (64 - i)) >> 1; if (e >= oi1) { oi = oi1; ++i; } }
    tab[e] = (unsigned short)(i * 40 + i + (e - oi));
  }
  const int w = tid >> 6, lane = tid & 63;
  const int n = (blockIdx.x << 2) + w;
  const int bt = n >> 5, c = n & 31;
  unsigned short* Uw = U[w];
#pragma unroll
  for (int t = 0; t < 5; ++t) ((ushort4*)Uw)[lane + (t << 6)] = make_ushort4(0, 0, 0, 0);
  if (lane < 32) Xl[w][lane] = X[(size_t)bt * 1024 + (c << 5) + lane];
  __syncthreads();

  const unsigned short* p = P + (size_t)bt * 16896 + c * 528;
#pragma unroll
  for (int e = 0; e < 9; ++e) {
    int idx = lane + (e << 6);
    if (idx < 528) Uw[tab[idx]] = p[idx];
  }

  const int col = lane & 31, hi = lane >> 5;
  bf16x8 fa0 = *(const bf16x8*)&Uw[col * 40 + (hi << 3)];
  bf16x8 fa1 = *(const bf16x8*)&Uw[col * 40 + 16 + (hi << 3)];
  f32x16 S = {0.f, 0.f, 0.f, 0.f, 0.f, 0.f, 0.f, 0.f, 0.f, 0.f, 0.f, 0.f, 0.f, 0.f, 0.f, 0.f};
  S = __builtin_amdgcn_mfma_f32_32x32x16_bf16(fa0, fa0, S, 0, 0, 0);
  S = __builtin_amdgcn_mfma_f32_32x32x16_bf16(fa1, fa1, S, 0, 0, 0);

  float css = 0.f;
#pragma unroll
  for (int r = 0; r < 16; ++r) css += S[r] * S[r];
  css += __shfl_xor(css, 32);
  float m = css;
#pragma unroll
  for (int off = 1; off < 32; off <<= 1) m = fmaxf(m, __shfl_xor(m, off));
  m = sqrtf(m);
  const float scale = alpha[n] / (m + EPS);

  const float* xw = Xl[w];
  f32x4 x0 = *(const f32x4*)&xw[(hi << 2)];
  f32x4 x1 = *(const f32x4*)&xw[8 + (hi << 2)];
  f32x4 x2 = *(const f32x4*)&xw[16 + (hi << 2)];
  f32x4 x3 = *(const f32x4*)&xw[24 + (hi << 2)];
  float y = 0.f;
#pragma unroll
  for (int r = 0; r < 4; ++r) y += x0[r] * S[r];
#pragma unroll
  for (int r = 0; r < 4; ++r) y += x1[r] * S[4 + r];
#pragma unroll
  for (int r = 0; r < 4; ++r) y += x2[r] * S[8 + r];
#pragma unroll
  for (int r = 0; r < 4; ++r) y += x3[r] * S[12 + r];
  y += __shfl_xor(y, 32);

  if (hi == 0) {
    out[(size_t)bt * 1024 + (c << 5) + col] = xw[col] - scale * y;
  }
}

extern "C" void kernel_launch(void* const* d_in, const int* in_sizes, int n_in,
                              void* d_out, int out_size, void* d_ws, size_t ws_size,
                              hipStream_t stream) {
  const float* param = (const float*)d_in[0];   // [2,2048,1024]
  const float* input = (const float*)d_in[1];   // [2,2048,1024]
  const float* W_uv  = (const float*)d_in[2];   // [16896,1024]
  const float* W_al  = (const float*)d_in[3];   // [32,1024]
  const float* b_al  = (const float*)d_in[4];   // [32]
  float* out = (float*)d_out;

  char* ws = (char*)d_ws;
  unsigned short* Ab    = (unsigned short*)(ws);                      //  8,388,608 B
  unsigned short* Wb    = (unsigned short*)(ws + 8388608);            // 34,603,008 B
  float*          alpha = (float*)(ws + 42991616);                    //    524,288 B
  unsigned short* Pp    = (unsigned short*)(ws + 43515904);           // 138,412,032 B

  (void)hipFuncSetAttribute((const void*)k_gemm8,
                            hipFuncAttributeMaxDynamicSharedMemorySize, 131072);

  k_head<<<8192, 256, 0, stream>>>(W_uv, Wb, param, W_al, b_al, alpha, Ab);
  k_gemm8<<<16 * 66, 512, 131072, stream>>>(Ab, Wb, Pp);
  k_epi<<<131072 / 4, 256, 0, stream>>>(Pp, input, alpha, out);
}

// Round 10
// 298.818 us; speedup vs baseline: 1.1754x; 1.1754x over previous
//
#include <hip/hip_runtime.h>
#include <hip/hip_bf16.h>
#include <stdint.h>

typedef float f32x4 __attribute__((ext_vector_type(4)));
typedef float f32x16 __attribute__((ext_vector_type(16)));
typedef __bf16 bf16x8 __attribute__((ext_vector_type(8)));

#define EPS 1e-5f

// ---- helpers ----
static __device__ __forceinline__ unsigned short f2bf(float f) {
  unsigned int u = __float_as_uint(f);
  unsigned int r = (u + 0x7fffu + ((u >> 16) & 1u)) >> 16;
  return (unsigned short)r;
}

static __device__ __forceinline__ void gload_lds16(const unsigned short* g, unsigned short* s) {
  __builtin_amdgcn_global_load_lds((const __attribute__((address_space(1))) unsigned int*)g,
                                   (__attribute__((address_space(3))) unsigned int*)s,
                                   16, 0, 0);
}

// ---- fused head: W_uv -> bf16 convert  |  alpha = sigmoid(A Wa^T + b) + A->bf16 ----
__global__ __launch_bounds__(256) void k_head(const float* __restrict__ Wsrc,
                                              unsigned short* __restrict__ Wb,
                                              const float* __restrict__ A,
                                              const float* __restrict__ Wa,
                                              const float* __restrict__ ba,
                                              float* __restrict__ alpha,
                                              unsigned short* __restrict__ Ab) {
  __shared__ __align__(16) float arow[1024];
  if (blockIdx.x < 4096) {
    const int n4 = (16896 * 1024) / 4;
    int idx = blockIdx.x * 256 + threadIdx.x;
    for (int i = idx; i < n4; i += 4096 * 256) {
      f32x4 v = ((const f32x4*)Wsrc)[i];
      ushort4 o;
      o.x = f2bf(v.x); o.y = f2bf(v.y); o.z = f2bf(v.z); o.w = f2bf(v.w);
      ((ushort4*)Wb)[i] = o;
    }
    return;
  }
  const int bt = blockIdx.x - 4096, tid = threadIdx.x;
  f32x4 v = ((const f32x4*)(A + (size_t)bt * 1024))[tid];
  ((f32x4*)arow)[tid] = v;
  ushort4 o;
  o.x = f2bf(v.x); o.y = f2bf(v.y); o.z = f2bf(v.z); o.w = f2bf(v.w);
  ((ushort4*)(Ab + (size_t)bt * 1024))[tid] = o;
  __syncthreads();
  const int c = tid >> 3, h = tid & 7;
  const float* wr = Wa + (size_t)c * 1024 + h * 128;
  const float* ar = arow + h * 128;
  float s = 0.f;
#pragma unroll 8
  for (int j = 0; j < 128; j += 4) {
    f32x4 wv = *(const f32x4*)(wr + j);
    s += wv.x * ar[j] + wv.y * ar[j + 1] + wv.z * ar[j + 2] + wv.w * ar[j + 3];
  }
  s += __shfl_down(s, 4);
  s += __shfl_down(s, 2);
  s += __shfl_down(s, 1);
  if (h == 0) {
    float z = s + ba[c];
    alpha[(size_t)bt * 32 + c] = 1.f / (1.f + __expf(-z));
  }
}

// ---- main GEMM: C[4096,16896] = A[4096,1024] @ W^T, bf16, 256^2 8-phase ----
// BM=BN=256 BK=64, 8 waves (2Mx4N), per-wave 128x64 out, 128 KiB LDS dbuf.
// tn-fast grid (tm-fast refuted on time, R9). Conflict-free swizzle (R6).
// This rev: 3-half-tile prefetch depth. Stage slots moved to the earliest
// legal phase (A0 at ph3/ph7, right after its buf region dies) so vmcnt(6)
// leaves exactly the next tile's {B0,B1,A0} in flight and the youngest
// forced load always has >=3 phases (~900+ cyc) of HBM cover.

#define SWZ(b) ((b) ^ ((((b) >> 7) & 7) << 4))

#define STG(mat, off, ldsoff) \
  gload_lds16((const unsigned short*)((const char*)(mat) + (unsigned)(off)), \
              (unsigned short*)(smem + (ldsoff) + widK))

#define READ_A(p0, p1, qm) do {                                                 \
  _Pragma("unroll") for (int _mi = 0; _mi < 4; ++_mi) {                         \
    af[_mi][0] = *(const bf16x8*)((p0) + (qm) * 8192 + _mi * 2048);             \
    af[_mi][1] = *(const bf16x8*)((p1) + (qm) * 8192 + _mi * 2048);             \
  } } while (0)

#define READ_B(p0, p1, qn) do {                                                 \
  _Pragma("unroll") for (int _ni = 0; _ni < 2; ++_ni) {                         \
    bfr[qn][_ni][0] = *(const bf16x8*)((p0) + (qn) * 4096 + _ni * 2048);        \
    bfr[qn][_ni][1] = *(const bf16x8*)((p1) + (qn) * 4096 + _ni * 2048);        \
  } } while (0)

#define MMA(qm, qn) do {                                                        \
  __builtin_amdgcn_s_setprio(1);                                                \
  _Pragma("unroll") for (int _mi = 0; _mi < 4; ++_mi)                           \
  _Pragma("unroll") for (int _ni = 0; _ni < 2; ++_ni)                           \
  _Pragma("unroll") for (int _ks = 0; _ks < 2; ++_ks)                           \
    acc[(qm) * 4 + _mi][(qn) * 2 + _ni] = __builtin_amdgcn_mfma_f32_16x16x32_bf16( \
        af[_mi][_ks], bfr[qn][_ni][_ks], acc[(qm) * 4 + _mi][(qn) * 2 + _ni], 0, 0, 0); \
  __builtin_amdgcn_s_setprio(0);                                                \
  } while (0)

#define PH_SYNC do {                                                            \
  __builtin_amdgcn_s_barrier();                                                 \
  asm volatile("s_waitcnt lgkmcnt(0)" ::: "memory");                            \
  __builtin_amdgcn_sched_barrier(0);                                            \
  } while (0)

#define ENDBAR __builtin_amdgcn_s_barrier()
#define VMW6 asm volatile("s_waitcnt vmcnt(6)" ::: "memory")
#define VMW0 asm volatile("s_waitcnt vmcnt(0)" ::: "memory")
#define LGKM8 asm volatile("s_waitcnt lgkmcnt(8)" ::: "memory")

__global__ __launch_bounds__(512, 2) void k_gemm8(const unsigned short* __restrict__ A,
                                                  const unsigned short* __restrict__ W,
                                                  unsigned short* __restrict__ C) {
  extern __shared__ char smem[];  // 131072 B: buf{0,1} x {A0 A1 | B0 B1} 16K regions
  const int bid = blockIdx.x;
  const int tm = bid / 66, tn = bid - tm * 66;  // tn-fast: consecutive blocks share A panel
  const int m0 = tm << 8, n0 = tn << 8;
  const int tid = threadIdx.x;
  const int lane = tid & 63;
  const int wid = tid >> 6;
  const int wm = wid >> 2, wn = wid & 3;
  const int fr = lane & 15, fq = lane >> 4;
  const int widK = wid * 1024;

  // staging global byte-offsets (pre-swizzled source, linear LDS dest)
  const int sb0 = SWZ(tid * 16);
  const int sb1 = SWZ(8192 + tid * 16);
  const int oB0_0 = (n0 + (sb0 >> 7)) * 2048 + (sb0 & 127);
  const int oB0_1 = (n0 + (sb1 >> 7)) * 2048 + (sb1 & 127);
  const int oB1_0 = oB0_0 + 128 * 2048;
  const int oB1_1 = oB0_1 + 128 * 2048;
  const int oA0_0 = (m0 + (sb0 >> 7)) * 2048 + (sb0 & 127);
  const int oA0_1 = (m0 + (sb1 >> 7)) * 2048 + (sb1 & 127);
  const int oA1_0 = oA0_0 + 128 * 2048;
  const int oA1_1 = oA0_1 + 128 * 2048;

  // ds_read bases: swizzled slot = ((ks<<2)|fq) ^ (fr&7); row term fr*128.
  const int lane0 = fr * 128 + ((fq ^ (fr & 7)) << 4);        // ks=0
  const int lane1 = fr * 128 + (((4 | fq) ^ (fr & 7)) << 4);  // ks=1
  char* const aK0b0 = smem + wm * 16384 + lane0;
  char* const aK1b0 = smem + wm * 16384 + lane1;
  char* const aK0b1 = aK0b0 + 65536;
  char* const aK1b1 = aK1b0 + 65536;
  char* const bb = smem + 32768 + (wn >> 1) * 16384 + (wn & 1) * 8192;
  char* const bK0b0 = bb + lane0;
  char* const bK1b0 = bb + lane1;
  char* const bK0b1 = bK0b0 + 65536;
  char* const bK1b1 = bK1b0 + 65536;

  f32x4 acc[8][4];
#pragma unroll
  for (int i = 0; i < 8; ++i)
#pragma unroll
    for (int j = 0; j < 4; ++j) acc[i][j] = (f32x4){0.f, 0.f, 0.f, 0.f};

  bf16x8 af[4][2];
  bf16x8 bfr[2][2][2];

  // prologue: K0 full (buf0, 8 loads) + K1 {B0,B1,A0} (buf1, 6 loads);
  // VMW6 waits K0 landed, K1's 6 stay in flight.
  STG(W, oB0_0, 32768); STG(W, oB0_1, 40960);
  STG(W, oB1_0, 49152); STG(W, oB1_1, 57344);
  STG(A, oA0_0, 0);     STG(A, oA0_1, 8192);
  STG(A, oA1_0, 16384); STG(A, oA1_1, 24576);
  STG(W, oB0_0 + 128, 98304);  STG(W, oB0_1 + 128, 106496);
  STG(W, oB1_0 + 128, 114688); STG(W, oB1_1 + 128, 122880);
  STG(A, oA0_0 + 128, 65536);  STG(A, oA0_1 + 128, 73728);
  VMW6;
  __builtin_amdgcn_s_barrier();

  for (int i = 0; i < 8; ++i) {
    const int kb1 = 256 * i + 128, kb2 = kb1 + 128, kb3 = kb2 + 128;
    // ph0: T0 q(0,0) | stage T1.A1 (buf1; free since prev ph6)
    READ_A(aK0b0, aK1b0, 0); READ_B(bK0b0, bK1b0, 0);
    STG(A, oA1_0 + kb1, 81920); STG(A, oA1_1 + kb1, 90112);
    LGKM8;
    PH_SYNC; MMA(0, 0); ENDBAR;
    // ph1: T0 q(0,1)
    READ_B(bK0b0, bK1b0, 1);
    PH_SYNC; MMA(0, 1); ENDBAR;
    // ph2: T0 q(1,0) | stage T2.B0 (buf0; B free since ph1)
    READ_A(aK0b0, aK1b0, 1);
    if (i < 7) { STG(W, oB0_0 + kb2, 32768); STG(W, oB0_1 + kb2, 40960); }
    PH_SYNC; MMA(1, 0); ENDBAR;
    // ph3: T0 q(1,1) | stage T2.B1 + T2.A0 (buf0.A free since ph2); VMW6 -> T1 landed
    if (i < 7) {
      STG(W, oB1_0 + kb2, 49152); STG(W, oB1_1 + kb2, 57344);
      STG(A, oA0_0 + kb2, 0);     STG(A, oA0_1 + kb2, 8192);
      VMW6;
    } else { VMW0; }
    PH_SYNC; MMA(1, 1); ENDBAR;
    // ph4: T1 q(0,0) | stage T2.A1 (buf0)
    READ_A(aK0b1, aK1b1, 0); READ_B(bK0b1, bK1b1, 0);
    if (i < 7) { STG(A, oA1_0 + kb2, 16384); STG(A, oA1_1 + kb2, 24576); }
    LGKM8;
    PH_SYNC; MMA(0, 0); ENDBAR;
    // ph5: T1 q(0,1)
    READ_B(bK0b1, bK1b1, 1);
    PH_SYNC; MMA(0, 1); ENDBAR;
    // ph6: T1 q(1,0) | stage T3.B0 (buf1)
    READ_A(aK0b1, aK1b1, 1);
    if (i < 7) { STG(W, oB0_0 + kb3, 98304); STG(W, oB0_1 + kb3, 106496); }
    PH_SYNC; MMA(1, 0); ENDBAR;
    // ph7: T1 q(1,1) | stage T3.B1 + T3.A0 (buf1.A free since ph6); VMW6 -> T2 landed
    if (i < 7) {
      STG(W, oB1_0 + kb3, 114688); STG(W, oB1_1 + kb3, 122880);
      STG(A, oA0_0 + kb3, 65536);  STG(A, oA0_1 + kb3, 73728);
      VMW6;
    }
    PH_SYNC; MMA(1, 1); ENDBAR;
  }

  // epilogue: C write (bf16), plain cached stores
#pragma unroll
  for (int am = 0; am < 8; ++am)
#pragma unroll
    for (int an = 0; an < 4; ++an)
#pragma unroll
      for (int r = 0; r < 4; ++r) {
        int row = m0 + (wm << 7) + (am << 4) + (fq << 2) + r;
        int col = n0 + (wn << 6) + (an << 4) + fr;
        C[(size_t)row * 16896 + col] = f2bf(acc[am][an][r]);
      }
}

// ---- epilogue: per n (one wave): U from triu params, S = U U^T via one
//      32x32x16 MFMA pair; reductions lane-local + 1 shfl (32x32 C/D layout).
__global__ __launch_bounds__(256) void k_epi(const unsigned short* __restrict__ P,
                                             const float* __restrict__ X,
                                             const float* __restrict__ alpha,
                                             float* __restrict__ out) {
  __shared__ __align__(16) unsigned short U[4][1280];  // [wave][32 rows x 40 stride]
  __shared__ __align__(16) float Xl[4][32];
  __shared__ unsigned short tab[528];
  const int tid = threadIdx.x;
  for (int e = tid; e < 528; e += 256) {
    float fi = (65.0f - sqrtf((float)(4225 - 8 * e))) * 0.5f;
    int i = (int)fi;
    int oi = (i * (65 - i)) >> 1;
    if (e < oi) { --i; oi = (i * (65 - i)) >> 1; }
    else { int oi1 = ((i + 1) * (64 - i)) >> 1; if (e >= oi1) { oi = oi1; ++i; } }
    tab[e] = (unsigned short)(i * 40 + i + (e - oi));
  }
  const int w = tid >> 6, lane = tid & 63;
  const int n = (blockIdx.x << 2) + w;
  const int bt = n >> 5, c = n & 31;
  unsigned short* Uw = U[w];
#pragma unroll
  for (int t = 0; t < 5; ++t) ((ushort4*)Uw)[lane + (t << 6)] = make_ushort4(0, 0, 0, 0);
  if (lane < 32) Xl[w][lane] = X[(size_t)bt * 1024 + (c << 5) + lane];
  __syncthreads();

  const unsigned short* p = P + (size_t)bt * 16896 + c * 528;
#pragma unroll
  for (int e = 0; e < 9; ++e) {
    int idx = lane + (e << 6);
    if (idx < 528) Uw[tab[idx]] = p[idx];
  }

  const int col = lane & 31, hi = lane >> 5;
  bf16x8 fa0 = *(const bf16x8*)&Uw[col * 40 + (hi << 3)];
  bf16x8 fa1 = *(const bf16x8*)&Uw[col * 40 + 16 + (hi << 3)];
  f32x16 S = {0.f, 0.f, 0.f, 0.f, 0.f, 0.f, 0.f, 0.f, 0.f, 0.f, 0.f, 0.f, 0.f, 0.f, 0.f, 0.f};
  S = __builtin_amdgcn_mfma_f32_32x32x16_bf16(fa0, fa0, S, 0, 0, 0);
  S = __builtin_amdgcn_mfma_f32_32x32x16_bf16(fa1, fa1, S, 0, 0, 0);

  float css = 0.f;
#pragma unroll
  for (int r = 0; r < 16; ++r) css += S[r] * S[r];
  css += __shfl_xor(css, 32);
  float m = css;
#pragma unroll
  for (int off = 1; off < 32; off <<= 1) m = fmaxf(m, __shfl_xor(m, off));
  m = sqrtf(m);
  const float scale = alpha[n] / (m + EPS);

  const float* xw = Xl[w];
  f32x4 x0 = *(const f32x4*)&xw[(hi << 2)];
  f32x4 x1 = *(const f32x4*)&xw[8 + (hi << 2)];
  f32x4 x2 = *(const f32x4*)&xw[16 + (hi << 2)];
  f32x4 x3 = *(const f32x4*)&xw[24 + (hi << 2)];
  float y = 0.f;
#pragma unroll
  for (int r = 0; r < 4; ++r) y += x0[r] * S[r];
#pragma unroll
  for (int r = 0; r < 4; ++r) y += x1[r] * S[4 + r];
#pragma unroll
  for (int r = 0; r < 4; ++r) y += x2[r] * S[8 + r];
#pragma unroll
  for (int r = 0; r < 4; ++r) y += x3[r] * S[12 + r];
  y += __shfl_xor(y, 32);

  if (hi == 0) {
    out[(size_t)bt * 1024 + (c << 5) + col] = xw[col] - scale * y;
  }
}

extern "C" void kernel_launch(void* const* d_in, const int* in_sizes, int n_in,
                              void* d_out, int out_size, void* d_ws, size_t ws_size,
                              hipStream_t stream) {
  const float* param = (const float*)d_in[0];   // [2,2048,1024]
  const float* input = (const float*)d_in[1];   // [2,2048,1024]
  const float* W_uv  = (const float*)d_in[2];   // [16896,1024]
  const float* W_al  = (const float*)d_in[3];   // [32,1024]
  const float* b_al  = (const float*)d_in[4];   // [32]
  float* out = (float*)d_out;

  char* ws = (char*)d_ws;
  unsigned short* Ab    = (unsigned short*)(ws);                      //  8,388,608 B
  unsigned short* Wb    = (unsigned short*)(ws + 8388608);            // 34,603,008 B
  float*          alpha = (float*)(ws + 42991616);                    //    524,288 B
  unsigned short* Pp    = (unsigned short*)(ws + 43515904);           // 138,412,032 B

  (void)hipFuncSetAttribute((const void*)k_gemm8,
                            hipFuncAttributeMaxDynamicSharedMemorySize, 131072);

  k_head<<<8192, 256, 0, stream>>>(W_uv, Wb, param, W_al, b_al, alpha, Ab);
  k_gemm8<<<16 * 66, 512, 131072, stream>>>(Ab, Wb, Pp);
  k_epi<<<131072 / 4, 256, 0, stream>>>(Pp, input, alpha, out);
}

// Round 11
// 290.630 us; speedup vs baseline: 1.2085x; 1.0282x over previous
//
#include <hip/hip_runtime.h>
#include <hip/hip_bf16.h>
#include <stdint.h>

typedef float f32x4 __attribute__((ext_vector_type(4)));
typedef float f32x16 __attribute__((ext_vector_type(16)));
typedef __bf16 bf16x8 __attribute__((ext_vector_type(8)));

#define EPS 1e-5f

// ---- helpers ----
static __device__ __forceinline__ unsigned short f2bf(float f) {
  unsigned int u = __float_as_uint(f);
  unsigned int r = (u + 0x7fffu + ((u >> 16) & 1u)) >> 16;
  return (unsigned short)r;
}

static __device__ __forceinline__ void gload_lds16(const unsigned short* g, unsigned short* s) {
  __builtin_amdgcn_global_load_lds((const __attribute__((address_space(1))) unsigned int*)g,
                                   (__attribute__((address_space(3))) unsigned int*)s,
                                   16, 0, 0);
}

// ---- fused head: W_uv -> bf16 convert  |  alpha = sigmoid(A Wa^T + b) + A->bf16 ----
__global__ __launch_bounds__(256) void k_head(const float* __restrict__ Wsrc,
                                              unsigned short* __restrict__ Wb,
                                              const float* __restrict__ A,
                                              const float* __restrict__ Wa,
                                              const float* __restrict__ ba,
                                              float* __restrict__ alpha,
                                              unsigned short* __restrict__ Ab) {
  __shared__ __align__(16) float arow[1024];
  if (blockIdx.x < 4096) {
    const int n4 = (16896 * 1024) / 4;
    int idx = blockIdx.x * 256 + threadIdx.x;
    for (int i = idx; i < n4; i += 4096 * 256) {
      f32x4 v = ((const f32x4*)Wsrc)[i];
      ushort4 o;
      o.x = f2bf(v.x); o.y = f2bf(v.y); o.z = f2bf(v.z); o.w = f2bf(v.w);
      ((ushort4*)Wb)[i] = o;
    }
    return;
  }
  const int bt = blockIdx.x - 4096, tid = threadIdx.x;
  f32x4 v = ((const f32x4*)(A + (size_t)bt * 1024))[tid];
  ((f32x4*)arow)[tid] = v;
  ushort4 o;
  o.x = f2bf(v.x); o.y = f2bf(v.y); o.z = f2bf(v.z); o.w = f2bf(v.w);
  ((ushort4*)(Ab + (size_t)bt * 1024))[tid] = o;
  __syncthreads();
  const int c = tid >> 3, h = tid & 7;
  const float* wr = Wa + (size_t)c * 1024 + h * 128;
  const float* ar = arow + h * 128;
  float s = 0.f;
#pragma unroll 8
  for (int j = 0; j < 128; j += 4) {
    f32x4 wv = *(const f32x4*)(wr + j);
    s += wv.x * ar[j] + wv.y * ar[j + 1] + wv.z * ar[j + 2] + wv.w * ar[j + 3];
  }
  s += __shfl_down(s, 4);
  s += __shfl_down(s, 2);
  s += __shfl_down(s, 1);
  if (h == 0) {
    float z = s + ba[c];
    alpha[(size_t)bt * 32 + c] = 1.f / (1.f + __expf(-z));
  }
}

// ---- main GEMM: C[4096,16896] = A[4096,1024] @ W^T, bf16, 256^2 8-phase ----
// FROZEN (R10 best: 177us). BM=BN=256 BK=64, 8 waves, 128 KiB LDS dbuf,
// tn-fast grid, conflict-free swizzle, 3-half-tile prefetch (vmcnt(6)).

#define SWZ(b) ((b) ^ ((((b) >> 7) & 7) << 4))

#define STG(mat, off, ldsoff) \
  gload_lds16((const unsigned short*)((const char*)(mat) + (unsigned)(off)), \
              (unsigned short*)(smem + (ldsoff) + widK))

#define READ_A(p0, p1, qm) do {                                                 \
  _Pragma("unroll") for (int _mi = 0; _mi < 4; ++_mi) {                         \
    af[_mi][0] = *(const bf16x8*)((p0) + (qm) * 8192 + _mi * 2048);             \
    af[_mi][1] = *(const bf16x8*)((p1) + (qm) * 8192 + _mi * 2048);             \
  } } while (0)

#define READ_B(p0, p1, qn) do {                                                 \
  _Pragma("unroll") for (int _ni = 0; _ni < 2; ++_ni) {                         \
    bfr[qn][_ni][0] = *(const bf16x8*)((p0) + (qn) * 4096 + _ni * 2048);        \
    bfr[qn][_ni][1] = *(const bf16x8*)((p1) + (qn) * 4096 + _ni * 2048);        \
  } } while (0)

#define MMA(qm, qn) do {                                                        \
  __builtin_amdgcn_s_setprio(1);                                                \
  _Pragma("unroll") for (int _mi = 0; _mi < 4; ++_mi)                           \
  _Pragma("unroll") for (int _ni = 0; _ni < 2; ++_ni)                           \
  _Pragma("unroll") for (int _ks = 0; _ks < 2; ++_ks)                           \
    acc[(qm) * 4 + _mi][(qn) * 2 + _ni] = __builtin_amdgcn_mfma_f32_16x16x32_bf16( \
        af[_mi][_ks], bfr[qn][_ni][_ks], acc[(qm) * 4 + _mi][(qn) * 2 + _ni], 0, 0, 0); \
  __builtin_amdgcn_s_setprio(0);                                                \
  } while (0)

#define PH_SYNC do {                                                            \
  __builtin_amdgcn_s_barrier();                                                 \
  asm volatile("s_waitcnt lgkmcnt(0)" ::: "memory");                            \
  __builtin_amdgcn_sched_barrier(0);                                            \
  } while (0)

#define ENDBAR __builtin_amdgcn_s_barrier()
#define VMW6 asm volatile("s_waitcnt vmcnt(6)" ::: "memory")
#define VMW0 asm volatile("s_waitcnt vmcnt(0)" ::: "memory")
#define LGKM8 asm volatile("s_waitcnt lgkmcnt(8)" ::: "memory")

__global__ __launch_bounds__(512, 2) void k_gemm8(const unsigned short* __restrict__ A,
                                                  const unsigned short* __restrict__ W,
                                                  unsigned short* __restrict__ C) {
  extern __shared__ char smem[];  // 131072 B: buf{0,1} x {A0 A1 | B0 B1} 16K regions
  const int bid = blockIdx.x;
  const int tm = bid / 66, tn = bid - tm * 66;  // tn-fast: consecutive blocks share A panel
  const int m0 = tm << 8, n0 = tn << 8;
  const int tid = threadIdx.x;
  const int lane = tid & 63;
  const int wid = tid >> 6;
  const int wm = wid >> 2, wn = wid & 3;
  const int fr = lane & 15, fq = lane >> 4;
  const int widK = wid * 1024;

  // staging global byte-offsets (pre-swizzled source, linear LDS dest)
  const int sb0 = SWZ(tid * 16);
  const int sb1 = SWZ(8192 + tid * 16);
  const int oB0_0 = (n0 + (sb0 >> 7)) * 2048 + (sb0 & 127);
  const int oB0_1 = (n0 + (sb1 >> 7)) * 2048 + (sb1 & 127);
  const int oB1_0 = oB0_0 + 128 * 2048;
  const int oB1_1 = oB0_1 + 128 * 2048;
  const int oA0_0 = (m0 + (sb0 >> 7)) * 2048 + (sb0 & 127);
  const int oA0_1 = (m0 + (sb1 >> 7)) * 2048 + (sb1 & 127);
  const int oA1_0 = oA0_0 + 128 * 2048;
  const int oA1_1 = oA0_1 + 128 * 2048;

  // ds_read bases: swizzled slot = ((ks<<2)|fq) ^ (fr&7); row term fr*128.
  const int lane0 = fr * 128 + ((fq ^ (fr & 7)) << 4);        // ks=0
  const int lane1 = fr * 128 + (((4 | fq) ^ (fr & 7)) << 4);  // ks=1
  char* const aK0b0 = smem + wm * 16384 + lane0;
  char* const aK1b0 = smem + wm * 16384 + lane1;
  char* const aK0b1 = aK0b0 + 65536;
  char* const aK1b1 = aK1b0 + 65536;
  char* const bb = smem + 32768 + (wn >> 1) * 16384 + (wn & 1) * 8192;
  char* const bK0b0 = bb + lane0;
  char* const bK1b0 = bb + lane1;
  char* const bK0b1 = bK0b0 + 65536;
  char* const bK1b1 = bK1b0 + 65536;

  f32x4 acc[8][4];
#pragma unroll
  for (int i = 0; i < 8; ++i)
#pragma unroll
    for (int j = 0; j < 4; ++j) acc[i][j] = (f32x4){0.f, 0.f, 0.f, 0.f};

  bf16x8 af[4][2];
  bf16x8 bfr[2][2][2];

  // prologue: K0 full (buf0, 8 loads) + K1 {B0,B1,A0} (buf1, 6 loads)
  STG(W, oB0_0, 32768); STG(W, oB0_1, 40960);
  STG(W, oB1_0, 49152); STG(W, oB1_1, 57344);
  STG(A, oA0_0, 0);     STG(A, oA0_1, 8192);
  STG(A, oA1_0, 16384); STG(A, oA1_1, 24576);
  STG(W, oB0_0 + 128, 98304);  STG(W, oB0_1 + 128, 106496);
  STG(W, oB1_0 + 128, 114688); STG(W, oB1_1 + 128, 122880);
  STG(A, oA0_0 + 128, 65536);  STG(A, oA0_1 + 128, 73728);
  VMW6;
  __builtin_amdgcn_s_barrier();

  for (int i = 0; i < 8; ++i) {
    const int kb1 = 256 * i + 128, kb2 = kb1 + 128, kb3 = kb2 + 128;
    // ph0: T0 q(0,0) | stage T1.A1 (buf1)
    READ_A(aK0b0, aK1b0, 0); READ_B(bK0b0, bK1b0, 0);
    STG(A, oA1_0 + kb1, 81920); STG(A, oA1_1 + kb1, 90112);
    LGKM8;
    PH_SYNC; MMA(0, 0); ENDBAR;
    // ph1: T0 q(0,1)
    READ_B(bK0b0, bK1b0, 1);
    PH_SYNC; MMA(0, 1); ENDBAR;
    // ph2: T0 q(1,0) | stage T2.B0 (buf0)
    READ_A(aK0b0, aK1b0, 1);
    if (i < 7) { STG(W, oB0_0 + kb2, 32768); STG(W, oB0_1 + kb2, 40960); }
    PH_SYNC; MMA(1, 0); ENDBAR;
    // ph3: T0 q(1,1) | stage T2.B1 + T2.A0; VMW6 -> T1 landed
    if (i < 7) {
      STG(W, oB1_0 + kb2, 49152); STG(W, oB1_1 + kb2, 57344);
      STG(A, oA0_0 + kb2, 0);     STG(A, oA0_1 + kb2, 8192);
      VMW6;
    } else { VMW0; }
    PH_SYNC; MMA(1, 1); ENDBAR;
    // ph4: T1 q(0,0) | stage T2.A1 (buf0)
    READ_A(aK0b1, aK1b1, 0); READ_B(bK0b1, bK1b1, 0);
    if (i < 7) { STG(A, oA1_0 + kb2, 16384); STG(A, oA1_1 + kb2, 24576); }
    LGKM8;
    PH_SYNC; MMA(0, 0); ENDBAR;
    // ph5: T1 q(0,1)
    READ_B(bK0b1, bK1b1, 1);
    PH_SYNC; MMA(0, 1); ENDBAR;
    // ph6: T1 q(1,0) | stage T3.B0 (buf1)
    READ_A(aK0b1, aK1b1, 1);
    if (i < 7) { STG(W, oB0_0 + kb3, 98304); STG(W, oB0_1 + kb3, 106496); }
    PH_SYNC; MMA(1, 0); ENDBAR;
    // ph7: T1 q(1,1) | stage T3.B1 + T3.A0; VMW6 -> T2 landed
    if (i < 7) {
      STG(W, oB1_0 + kb3, 114688); STG(W, oB1_1 + kb3, 122880);
      STG(A, oA0_0 + kb3, 65536);  STG(A, oA0_1 + kb3, 73728);
      VMW6;
    }
    PH_SYNC; MMA(1, 1); ENDBAR;
  }

  // epilogue: C write (bf16), plain cached stores
#pragma unroll
  for (int am = 0; am < 8; ++am)
#pragma unroll
    for (int an = 0; an < 4; ++an)
#pragma unroll
      for (int r = 0; r < 4; ++r) {
        int row = m0 + (wm << 7) + (am << 4) + (fq << 2) + r;
        int col = n0 + (wn << 6) + (an << 4) + fr;
        C[(size_t)row * 16896 + col] = f2bf(acc[am][an][r]);
      }
}

// ---- epilogue: 16 n per block (4 waves x 4 serial n). tab built once per
//      block; single wave owns its U buffer so zero/scatter/frag-read need
//      no barriers (same-wave DS ops are in-order). X staged as one fully
//      coalesced 2KB block load. S = U U^T via 32x32x16 MFMA pair.
__global__ __launch_bounds__(256) void k_epi(const unsigned short* __restrict__ P,
                                             const float* __restrict__ X,
                                             const float* __restrict__ alpha,
                                             float* __restrict__ out) {
  __shared__ __align__(16) unsigned short U[4][1280];  // [wave][32 rows x 40 stride]
  __shared__ __align__(16) float Xl[512];              // 16 n x 32 floats, linear
  __shared__ unsigned short tab[528];
  const int tid = threadIdx.x;
  for (int e = tid; e < 528; e += 256) {
    float fi = (65.0f - sqrtf((float)(4225 - 8 * e))) * 0.5f;
    int i = (int)fi;
    int oi = (i * (65 - i)) >> 1;
    if (e < oi) { --i; oi = (i * (65 - i)) >> 1; }
    else { int oi1 = ((i + 1) * (64 - i)) >> 1; if (e >= oi1) { oi = oi1; ++i; } }
    tab[e] = (unsigned short)(i * 40 + i + (e - oi));
  }
  const int w = tid >> 6, lane = tid & 63;
  const int nblk = blockIdx.x << 4;            // 16 consecutive n, same bt
  const int btB = nblk >> 5, c0 = nblk & 31;   // block bt and base c
  // coalesced X stage: 512 consecutive floats (16 c-slices of 32)
  if (tid < 128)
    ((f32x4*)Xl)[tid] = ((const f32x4*)(X + (size_t)btB * 1024 + c0 * 32))[tid];
  __syncthreads();  // tab + Xl ready

  unsigned short* Uw = U[w];
  const int col = lane & 31, hi = lane >> 5;

#pragma unroll
  for (int it = 0; it < 4; ++it) {
    const int li = (w << 2) + it;      // local n index 0..15
    const int n = nblk + li;
    const int c = c0 + li;
    // zero U (same-wave DS order guarantees visibility to later reads)
#pragma unroll
    for (int t = 0; t < 5; ++t) ((ushort4*)Uw)[lane + (t << 6)] = make_ushort4(0, 0, 0, 0);
    // scatter 528 triu params
    const unsigned short* p = P + (size_t)btB * 16896 + c * 528;
#pragma unroll
    for (int e = 0; e < 9; ++e) {
      int idx = lane + (e << 6);
      if (idx < 528) Uw[tab[idx]] = p[idx];
    }
    bf16x8 fa0 = *(const bf16x8*)&Uw[col * 40 + (hi << 3)];
    bf16x8 fa1 = *(const bf16x8*)&Uw[col * 40 + 16 + (hi << 3)];
    f32x16 S = {0.f, 0.f, 0.f, 0.f, 0.f, 0.f, 0.f, 0.f,
                0.f, 0.f, 0.f, 0.f, 0.f, 0.f, 0.f, 0.f};
    S = __builtin_amdgcn_mfma_f32_32x32x16_bf16(fa0, fa0, S, 0, 0, 0);
    S = __builtin_amdgcn_mfma_f32_32x32x16_bf16(fa1, fa1, S, 0, 0, 0);
    // lane holds S[row=(r&3)+8*(r>>2)+4*hi][col], r=0..15

    float css = 0.f;
#pragma unroll
    for (int r = 0; r < 16; ++r) css += S[r] * S[r];
    css += __shfl_xor(css, 32);
    float m = css;
#pragma unroll
    for (int off = 1; off < 32; off <<= 1) m = fmaxf(m, __shfl_xor(m, off));
    m = sqrtf(m);
    const float scale = alpha[n] / (m + EPS);

    const float* xw = Xl + li * 32;
    f32x4 x0 = *(const f32x4*)&xw[(hi << 2)];
    f32x4 x1 = *(const f32x4*)&xw[8 + (hi << 2)];
    f32x4 x2 = *(const f32x4*)&xw[16 + (hi << 2)];
    f32x4 x3 = *(const f32x4*)&xw[24 + (hi << 2)];
    float y = 0.f;
#pragma unroll
    for (int r = 0; r < 4; ++r) y += x0[r] * S[r];
#pragma unroll
    for (int r = 0; r < 4; ++r) y += x1[r] * S[4 + r];
#pragma unroll
    for (int r = 0; r < 4; ++r) y += x2[r] * S[8 + r];
#pragma unroll
    for (int r = 0; r < 4; ++r) y += x3[r] * S[12 + r];
    y += __shfl_xor(y, 32);

    if (hi == 0) {
      out[(size_t)btB * 1024 + c * 32 + col] = xw[col] - scale * y;
    }
  }
}

extern "C" void kernel_launch(void* const* d_in, const int* in_sizes, int n_in,
                              void* d_out, int out_size, void* d_ws, size_t ws_size,
                              hipStream_t stream) {
  const float* param = (const float*)d_in[0];   // [2,2048,1024]
  const float* input = (const float*)d_in[1];   // [2,2048,1024]
  const float* W_uv  = (const float*)d_in[2];   // [16896,1024]
  const float* W_al  = (const float*)d_in[3];   // [32,1024]
  const float* b_al  = (const float*)d_in[4];   // [32]
  float* out = (float*)d_out;

  char* ws = (char*)d_ws;
  unsigned short* Ab    = (unsigned short*)(ws);                      //  8,388,608 B
  unsigned short* Wb    = (unsigned short*)(ws + 8388608);            // 34,603,008 B
  float*          alpha = (float*)(ws + 42991616);                    //    524,288 B
  unsigned short* Pp    = (unsigned short*)(ws + 43515904);           // 138,412,032 B

  (void)hipFuncSetAttribute((const void*)k_gemm8,
                            hipFuncAttributeMaxDynamicSharedMemorySize, 131072);

  k_head<<<8192, 256, 0, stream>>>(W_uv, Wb, param, W_al, b_al, alpha, Ab);
  k_gemm8<<<16 * 66, 512, 131072, stream>>>(Ab, Wb, Pp);
  k_epi<<<131072 / 16, 256, 0, stream>>>(Pp, input, alpha, out);
}